// Round 4
// baseline (2646.029 us; speedup 1.0000x reference)
//
#include <hip/hip_runtime.h>
#include <hip/hip_bf16.h>
#include <math.h>

// Problem constants
#define HID 256
#define LAT 128
#define BB  32
#define TT  32
#define EE  2048
#define NBR 10
#define VV  6
#define TE  (TT*EE)          // 65536
#define NROWS (TE + BB)      // 65568
#define MROWS (TE + 1)       // 65537

__device__ __forceinline__ float sigmoidf_(float x) { return 1.0f / (1.0f + expf(-x)); }

// ---------------------------------------------------------------------------
// GEMM tile core: C[m][n] = sum_{k<256} A[m*256+k] * W[n*ldw + koff + k]
// Tile 64x64, 256 threads, each thread 4x4 outputs, K chunk 16.
// W4: W rows are 16B-aligned (ldw%4==0, koff%4==0) -> float4 loads.
// ---------------------------------------------------------------------------
template<bool W4>
__device__ __forceinline__ void gemm_body(
    const float* __restrict__ A, int Mrows,
    const float* __restrict__ W, int ldw, int koff,
    float* __restrict__ C, int m0, int n0)
{
    __shared__ float As[16][64];
    __shared__ float Ws[16][64];

    const int tid = threadIdx.x;
    const int tx = tid & 15;      // 0..15 -> n
    const int ty = tid >> 4;      // 0..15 -> m
    const int lm  = tid >> 2;     // 0..63 row/col within tile for loads
    const int lk4 = (tid & 3) * 4;

    float acc[4][4] = {};

    for (int k0 = 0; k0 < 256; k0 += 16) {
        {
            int row = m0 + lm;
            float4 av;
            if (row < Mrows) {
                av = *reinterpret_cast<const float4*>(A + (size_t)row * 256 + k0 + lk4);
            } else {
                av = make_float4(0.f, 0.f, 0.f, 0.f);
            }
            As[lk4 + 0][lm] = av.x;
            As[lk4 + 1][lm] = av.y;
            As[lk4 + 2][lm] = av.z;
            As[lk4 + 3][lm] = av.w;
        }
        {
            const float* wp = W + (size_t)(n0 + lm) * ldw + koff + k0 + lk4;
            if (W4) {
                float4 wv = *reinterpret_cast<const float4*>(wp);
                Ws[lk4 + 0][lm] = wv.x;
                Ws[lk4 + 1][lm] = wv.y;
                Ws[lk4 + 2][lm] = wv.z;
                Ws[lk4 + 3][lm] = wv.w;
            } else {
                Ws[lk4 + 0][lm] = wp[0];
                Ws[lk4 + 1][lm] = wp[1];
                Ws[lk4 + 2][lm] = wp[2];
                Ws[lk4 + 3][lm] = wp[3];
            }
        }
        __syncthreads();
        #pragma unroll
        for (int k = 0; k < 16; ++k) {
            float a[4], b[4];
            #pragma unroll
            for (int i = 0; i < 4; ++i) a[i] = As[k][ty * 4 + i];
            #pragma unroll
            for (int j = 0; j < 4; ++j) b[j] = Ws[k][tx * 4 + j];
            #pragma unroll
            for (int i = 0; i < 4; ++i)
                #pragma unroll
                for (int j = 0; j < 4; ++j)
                    acc[i][j] += a[i] * b[j];
        }
        __syncthreads();
    }

    #pragma unroll
    for (int i = 0; i < 4; ++i) {
        int row = m0 + ty * 4 + i;
        if (row < Mrows) {
            float4 v = make_float4(acc[i][0], acc[i][1], acc[i][2], acc[i][3]);
            *reinterpret_cast<float4*>(C + (size_t)row * 256 + n0 + tx * 4) = v;
        }
    }
}

// Generic scalar-W GEMM (ldw=262 cases).
__global__ __launch_bounds__(256) void gemm_nt(
    const float* __restrict__ A, int Mrows,
    const float* __restrict__ W, int ldw, int koff,
    float* __restrict__ C)
{
    gemm_body<false>(A, Mrows, W, ldw, koff, C, blockIdx.x * 64, blockIdx.y * 64);
}

// float4-W GEMM (ldw%4==0, koff=0).
__global__ __launch_bounds__(256) void gemm_nt_v(
    const float* __restrict__ A, int Mrows,
    const float* __restrict__ W, int ldw,
    float* __restrict__ C)
{
    gemm_body<true>(A, Mrows, W, ldw, 0, C, blockIdx.x * 64, blockIdx.y * 64);
}

// Fused pair of [EE,256]x[256,256] GEMMs (z-pre and h-pre), selected by z.
__global__ __launch_bounds__(256) void gemm2_nt(
    const float* __restrict__ A0, const float* __restrict__ W0, float* __restrict__ C0,
    const float* __restrict__ A1, const float* __restrict__ W1, float* __restrict__ C1)
{
    const float* A = blockIdx.z ? A1 : A0;
    const float* W = blockIdx.z ? W1 : W0;
    float*       C = blockIdx.z ? C1 : C0;
    gemm_body<false>(A, EE, W, 262, VV, C, blockIdx.x * 64, blockIdx.y * 64);
}

// ---------------------------------------------------------------------------
// Fused combine + Ur-GEMM. A-tile = new_h computed inline from zpre/ppre/sumh.
// y==0 blocks also write the H rows. W = Ur_w [256][256] (float4 path).
// Grid: (EE/64, 4). Also writes UrH rows for this step.
// ---------------------------------------------------------------------------
__global__ __launch_bounds__(256) void combine_ur_gemm(
    const float* __restrict__ zpre, const float* __restrict__ ppre,
    const float* __restrict__ sumh, const int* __restrict__ labels,
    const float* __restrict__ Wz_w, const float* __restrict__ Wz_b,
    const float* __restrict__ Wh_w, const float* __restrict__ Wh_b,
    const float* __restrict__ Ur_w,
    float* __restrict__ Hrow,      // H + (1+t*E)*256
    float* __restrict__ UrHrow)    // UrH + (1+t*E)*256
{
    __shared__ float As[16][64];
    __shared__ float Ws[16][64];

    const int tid = threadIdx.x;
    const int tx = tid & 15;
    const int ty = tid >> 4;
    const int lm  = tid >> 2;
    const int lk4 = (tid & 3) * 4;
    const int m0 = blockIdx.x * 64;
    const int n0 = blockIdx.y * 64;

    const int row = m0 + lm;              // 0..EE-1, always in range
    const int lbl = labels[row];

    float acc[4][4] = {};

    for (int k0 = 0; k0 < 256; k0 += 16) {
        // ---- A tile: compute new_h[row][k0+lk4 .. +4) inline ----
        {
            const size_t off = (size_t)row * 256 + k0 + lk4;
            float4 zv = *reinterpret_cast<const float4*>(zpre + off);
            float4 pv = *reinterpret_cast<const float4*>(ppre + off);
            float4 sv = *reinterpret_cast<const float4*>(sumh + off);
            float zz[4] = {zv.x, zv.y, zv.z, zv.w};
            float pp[4] = {pv.x, pv.y, pv.z, pv.w};
            float ss[4] = {sv.x, sv.y, sv.z, sv.w};
            float nh[4];
            #pragma unroll
            for (int j = 0; j < 4; ++j) {
                const int h = k0 + lk4 + j;
                const float z  = sigmoidf_(zz[j] + Wz_w[h * 262 + lbl] + Wz_b[h]);
                const float ph = tanhf(pp[j] + Wh_w[h * 262 + lbl] + Wh_b[h]);
                nh[j] = (1.0f - z) * ss[j] + z * ph;
                As[lk4 + j][lm] = nh[j];
            }
            if (blockIdx.y == 0) {
                *reinterpret_cast<float4*>(Hrow + off) =
                    make_float4(nh[0], nh[1], nh[2], nh[3]);
            }
        }
        // ---- W tile from Ur_w (ldw 256, float4) ----
        {
            const float* wp = Ur_w + (size_t)(n0 + lm) * 256 + k0 + lk4;
            float4 wv = *reinterpret_cast<const float4*>(wp);
            Ws[lk4 + 0][lm] = wv.x;
            Ws[lk4 + 1][lm] = wv.y;
            Ws[lk4 + 2][lm] = wv.z;
            Ws[lk4 + 3][lm] = wv.w;
        }
        __syncthreads();
        #pragma unroll
        for (int k = 0; k < 16; ++k) {
            float a[4], b[4];
            #pragma unroll
            for (int i = 0; i < 4; ++i) a[i] = As[k][ty * 4 + i];
            #pragma unroll
            for (int j = 0; j < 4; ++j) b[j] = Ws[k][tx * 4 + j];
            #pragma unroll
            for (int i = 0; i < 4; ++i)
                #pragma unroll
                for (int j = 0; j < 4; ++j)
                    acc[i][j] += a[i] * b[j];
        }
        __syncthreads();
    }

    #pragma unroll
    for (int i = 0; i < 4; ++i) {
        const int r = m0 + ty * 4 + i;
        float4 v = make_float4(acc[i][0], acc[i][1], acc[i][2], acc[i][3]);
        *reinterpret_cast<float4*>(UrHrow + (size_t)r * 256 + n0 + tx * 4) = v;
    }
}

// ---------------------------------------------------------------------------
// Fused relu + stop-head second GEMM.
// A-tile = relu(pre[row] + Ui_w[:,lbl] + Ui_b) inline; W = U_w [256][384] koff 0.
// Grid: (ceil(NROWS/64), 4). C = curO (pre2).
// ---------------------------------------------------------------------------
__global__ __launch_bounds__(256) void relu_gemm(
    const float* __restrict__ pre,
    const int* __restrict__ cur_labels, const int* __restrict__ root_labels,
    const float* __restrict__ Ui_w, const float* __restrict__ Ui_b,
    const float* __restrict__ U_w,
    float* __restrict__ C)
{
    __shared__ float As[16][64];
    __shared__ float Ws[16][64];

    const int tid = threadIdx.x;
    const int tx = tid & 15;
    const int ty = tid >> 4;
    const int lm  = tid >> 2;
    const int lk4 = (tid & 3) * 4;
    const int m0 = blockIdx.x * 64;
    const int n0 = blockIdx.y * 64;

    const int row = m0 + lm;
    const bool ok = row < NROWS;
    const int lbl = ok ? ((row < TE) ? cur_labels[row] : root_labels[row - TE]) : 0;

    float acc[4][4] = {};

    for (int k0 = 0; k0 < 256; k0 += 16) {
        {
            float a4[4] = {0.f, 0.f, 0.f, 0.f};
            if (ok) {
                const size_t off = (size_t)row * 256 + k0 + lk4;
                float4 pv = *reinterpret_cast<const float4*>(pre + off);
                float pp[4] = {pv.x, pv.y, pv.z, pv.w};
                #pragma unroll
                for (int j = 0; j < 4; ++j) {
                    const int h = k0 + lk4 + j;
                    a4[j] = fmaxf(pp[j] + Ui_w[h * 262 + lbl] + Ui_b[h], 0.f);
                }
            }
            #pragma unroll
            for (int j = 0; j < 4; ++j) As[lk4 + j][lm] = a4[j];
        }
        {
            const float* wp = U_w + (size_t)(n0 + lm) * 384 + k0 + lk4;
            float4 wv = *reinterpret_cast<const float4*>(wp);
            Ws[lk4 + 0][lm] = wv.x;
            Ws[lk4 + 1][lm] = wv.y;
            Ws[lk4 + 2][lm] = wv.z;
            Ws[lk4 + 3][lm] = wv.w;
        }
        __syncthreads();
        #pragma unroll
        for (int k = 0; k < 16; ++k) {
            float a[4], b[4];
            #pragma unroll
            for (int i = 0; i < 4; ++i) a[i] = As[k][ty * 4 + i];
            #pragma unroll
            for (int j = 0; j < 4; ++j) b[j] = Ws[k][tx * 4 + j];
            #pragma unroll
            for (int i = 0; i < 4; ++i)
                #pragma unroll
                for (int j = 0; j < 4; ++j)
                    acc[i][j] += a[i] * b[j];
        }
        __syncthreads();
    }

    #pragma unroll
    for (int i = 0; i < 4; ++i) {
        const int r = m0 + ty * 4 + i;
        if (r < NROWS) {
            float4 v = make_float4(acc[i][0], acc[i][1], acc[i][2], acc[i][3]);
            *reinterpret_cast<float4*>(C + (size_t)r * 256 + n0 + tx * 4) = v;
        }
    }
}

// ---------------------------------------------------------------------------
// Per-step gather: sum_h, gated (r*h sum), cur_o.
// ---------------------------------------------------------------------------
__global__ __launch_bounds__(256) void step_gather(
    const float* __restrict__ H, const float* __restrict__ UrH,
    const int* __restrict__ nih, const int* __restrict__ nio,
    const int* __restrict__ labels,
    const float* __restrict__ Wr_w, const float* __restrict__ Wr_b,
    const float* __restrict__ Ur_b,
    float* __restrict__ sum_h, float* __restrict__ gated,
    float* __restrict__ curO)
{
    const int e = blockIdx.x;
    const int h = threadIdx.x;
    __shared__ int idxh[NBR], idxo[NBR];
    if (h < NBR) {
        idxh[h] = nih[e * NBR + h];
        idxo[h] = nio[e * NBR + h];
    }
    __syncthreads();
    const int lbl = labels[e];
    const float wr = Wr_w[h * VV + lbl] + Wr_b[h] + Ur_b[h];
    float s = 0.f, g = 0.f, o = 0.f;
    #pragma unroll
    for (int nb = 0; nb < NBR; ++nb) {
        const float hv = H[(size_t)idxh[nb] * 256 + h];
        const float uv = UrH[(size_t)idxh[nb] * 256 + h];
        const float r = sigmoidf_(wr + uv);
        s += hv;
        g += r * hv;
        o += H[(size_t)idxo[nb] * 256 + h];
    }
    sum_h[e * 256 + h] = s;
    gated[e * 256 + h] = g;
    curO[(size_t)e * 256 + h] = o;
}

// ---------------------------------------------------------------------------
// latent @ {W_w,U_w}[:,256:384].T  -> latW / latW2 [B][256]
// ---------------------------------------------------------------------------
__global__ __launch_bounds__(256) void lat_gemm2(
    const float* __restrict__ lat,
    const float* __restrict__ W0, const float* __restrict__ W1,
    float* __restrict__ out0, float* __restrict__ out1)
{
    const int b = blockIdx.x;
    const int h = threadIdx.x;
    const float* W  = blockIdx.y ? W1 : W0;
    float* out      = blockIdx.y ? out1 : out0;
    float acc = 0.f;
    #pragma unroll 4
    for (int k = 0; k < LAT; ++k)
        acc += lat[b * LAT + k] * W[h * 384 + 256 + k];
    out[b * 256 + h] = acc;
}

// ---------------------------------------------------------------------------
// root_o[i] = sum_nb H[root_nei_idx[i][nb]]  -> curO rows TE..TE+B-1
// ---------------------------------------------------------------------------
__global__ __launch_bounds__(256) void root_o_kernel(
    const float* __restrict__ H, const int* __restrict__ rni,
    float* __restrict__ curO_root)
{
    const int b = blockIdx.x;
    const int h = threadIdx.x;
    float o = 0.f;
    #pragma unroll
    for (int nb = 0; nb < NBR; ++nb)
        o += H[(size_t)rni[b * NBR + nb] * 256 + h];
    curO_root[(size_t)b * 256 + h] = o;
}

// ---------------------------------------------------------------------------
// Pred head: one block per row.
// ---------------------------------------------------------------------------
__global__ __launch_bounds__(256) void pred_head(
    const float* __restrict__ pre, const float* __restrict__ latW,
    const float* __restrict__ W_b,
    const float* __restrict__ Wo_w, const float* __restrict__ Wo_b,
    const int* __restrict__ contexts, const int* __restrict__ direction,
    const int* __restrict__ ptgt, const int* __restrict__ root_labels,
    float* __restrict__ part)                                  // [NROWS][3]
{
    const int r = blockIdx.x;
    const int h = threadIdx.x;
    int tgt;
    float mask, v;
    if (r < TE) {
        const int c = contexts[r];
        tgt = ptgt[r];
        mask = (direction[r] == 1) ? 1.f : 0.f;
        v = pre[(size_t)r * 256 + h] + latW[c * 256 + h] + W_b[h];
    } else {
        const int i = r - TE;
        tgt = root_labels[i];
        mask = 1.f;
        v = latW[i * 256 + h] + W_b[h];
    }
    v = fmaxf(v, 0.f);

    __shared__ float red[VV][4];
    const int lane = h & 63, wv = h >> 6;
    #pragma unroll
    for (int c = 0; c < VV; ++c) {
        float x = v * Wo_w[c * 256 + h];
        #pragma unroll
        for (int off = 32; off; off >>= 1) x += __shfl_down(x, off);
        if (lane == 0) red[c][wv] = x;
    }
    __syncthreads();
    if (h == 0) {
        float sc[VV];
        #pragma unroll
        for (int c = 0; c < VV; ++c)
            sc[c] = red[c][0] + red[c][1] + red[c][2] + red[c][3] + Wo_b[c];
        float mx = sc[0];
        int am = 0;
        #pragma unroll
        for (int c = 1; c < VV; ++c)
            if (sc[c] > mx) { mx = sc[c]; am = c; }
        float se = 0.f;
        #pragma unroll
        for (int c = 0; c < VV; ++c) se += expf(sc[c] - mx);
        const float lse = mx + logf(se);
        const float ce = lse - sc[tgt];
        part[(size_t)r * 3 + 0] = ce * mask;
        part[(size_t)r * 3 + 1] = mask;
        part[(size_t)r * 3 + 2] = (am == tgt) ? mask : 0.f;
    }
}

// ---------------------------------------------------------------------------
// Stop head final: s, BCE loss, acc.
// ---------------------------------------------------------------------------
__global__ __launch_bounds__(256) void stop_head(
    const float* __restrict__ pre2, const float* __restrict__ latW2,
    const float* __restrict__ U_b,
    const float* __restrict__ Uo_w, const float* __restrict__ Uo_b,
    const int* __restrict__ contexts, const int* __restrict__ direction,
    float* __restrict__ part2)                                 // [NROWS][2]
{
    const int r = blockIdx.x;
    const int h = threadIdx.x;
    const int c = (r < TE) ? contexts[r] : (r - TE);
    const float tgt = (r < TE) ? (float)direction[r] : 0.f;
    float v = fmaxf(pre2[(size_t)r * 256 + h] + latW2[c * 256 + h] + U_b[h], 0.f);
    float x = v * Uo_w[h];
    #pragma unroll
    for (int off = 32; off; off >>= 1) x += __shfl_down(x, off);
    __shared__ float red[4];
    const int lane = h & 63, wv = h >> 6;
    if (lane == 0) red[wv] = x;
    __syncthreads();
    if (h == 0) {
        const float s = red[0] + red[1] + red[2] + red[3] + Uo_b[0];
        const float loss = fmaxf(s, 0.f) - s * tgt + log1pf(expf(-fabsf(s)));
        const float stop = (s >= 0.f) ? 1.f : 0.f;
        part2[(size_t)r * 2 + 0] = loss;
        part2[(size_t)r * 2 + 1] = (stop == tgt) ? 1.f : 0.f;
    }
}

// ---------------------------------------------------------------------------
// Reduce partials -> accum[5]
// ---------------------------------------------------------------------------
__global__ __launch_bounds__(256) void reduce_parts(
    const float* __restrict__ p1, const float* __restrict__ p2,
    float* __restrict__ accum)
{
    float a[5] = {0.f, 0.f, 0.f, 0.f, 0.f};
    const int stride = gridDim.x * blockDim.x;
    for (int r = blockIdx.x * blockDim.x + threadIdx.x; r < NROWS; r += stride) {
        a[0] += p1[(size_t)r * 3 + 0];
        a[1] += p1[(size_t)r * 3 + 1];
        a[2] += p1[(size_t)r * 3 + 2];
        a[3] += p2[(size_t)r * 2 + 0];
        a[4] += p2[(size_t)r * 2 + 1];
    }
    __shared__ float red[5][4];
    const int lane = threadIdx.x & 63, wv = threadIdx.x >> 6;
    #pragma unroll
    for (int i = 0; i < 5; ++i) {
        float x = a[i];
        #pragma unroll
        for (int off = 32; off; off >>= 1) x += __shfl_down(x, off);
        if (lane == 0) red[i][wv] = x;
    }
    __syncthreads();
    if (threadIdx.x < 5) {
        const float s = red[threadIdx.x][0] + red[threadIdx.x][1] +
                        red[threadIdx.x][2] + red[threadIdx.x][3];
        atomicAdd(&accum[threadIdx.x], s);
    }
}

__global__ void finalize(const float* __restrict__ accum, float* __restrict__ out)
{
    if (threadIdx.x == 0) {
        out[0] = accum[0] / (float)BB;            // pred_loss
        out[1] = accum[3] / (float)BB;            // stop_loss
        out[2] = accum[2] / accum[1];             // pred_acc
        out[3] = accum[4] / (float)NROWS;         // stop_acc
    }
}

// ---------------------------------------------------------------------------
extern "C" void kernel_launch(void* const* d_in, const int* in_sizes, int n_in,
                              void* d_out, int out_size, void* d_ws, size_t ws_size,
                              hipStream_t stream)
{
    const float* lat  = (const float*)d_in[0];
    const int*   nih  = (const int*)d_in[1];
    const int*   nio  = (const int*)d_in[2];
    const int*   lbl  = (const int*)d_in[3];
    const int*   ctx  = (const int*)d_in[4];
    const int*   dir  = (const int*)d_in[5];
    const int*   ptg  = (const int*)d_in[6];
    const int*   rlb  = (const int*)d_in[7];
    const int*   rni  = (const int*)d_in[8];
    const float* Wz_w = (const float*)d_in[9],  *Wz_b = (const float*)d_in[10];
    const float* Wr_w = (const float*)d_in[11], *Wr_b = (const float*)d_in[12];
    const float* Ur_w = (const float*)d_in[13], *Ur_b = (const float*)d_in[14];
    const float* Wh_w = (const float*)d_in[15], *Wh_b = (const float*)d_in[16];
    const float* W_w  = (const float*)d_in[17], *W_b  = (const float*)d_in[18];
    const float* Wo_w = (const float*)d_in[19], *Wo_b = (const float*)d_in[20];
    const float* U_w  = (const float*)d_in[21], *U_b  = (const float*)d_in[22];
    const float* Uo_w = (const float*)d_in[23], *Uo_b = (const float*)d_in[24];
    const float* Ui_w = (const float*)d_in[25], *Ui_b = (const float*)d_in[26];

    float* f = (float*)d_ws;
    const size_t RB = (size_t)NROWS * 256;         // ~64 MB each
    float* H     = f;                              // rows 0..TE (row 0 stays zero)
    float* UrH   = H + RB;                         // H @ Ur.T; later head scratch
    float* curO  = UrH + RB;                       // [NROWS][256]; later pre2
    float* sumh  = curO + RB;                      // [E][256]
    float* gated = sumh + (size_t)EE * 256;
    float* zpre  = gated + (size_t)EE * 256;
    float* ppre  = zpre + (size_t)EE * 256;
    float* latW  = ppre + (size_t)EE * 256;        // [B][256]
    float* latW2 = latW + BB * 256;
    float* part1 = latW2 + BB * 256;               // [NROWS][3]
    float* part2 = part1 + (size_t)NROWS * 3;      // [NROWS][2]
    float* accum = part2 + (size_t)NROWS * 2;      // [8]
    // total ~211 MB of d_ws

    // Unwritten H/UrH rows must read as zero (ws re-poisoned each launch)
    hipMemsetAsync(H, 0, RB * 2 * sizeof(float), stream);
    hipMemsetAsync(accum, 0, 8 * sizeof(float), stream);

    lat_gemm2<<<dim3(BB, 2), 256, 0, stream>>>(lat, W_w, U_w, latW, latW2);

    for (int t = 0; t < TT; ++t) {
        const size_t ro = (size_t)t * EE;
        step_gather<<<EE, 256, 0, stream>>>(
            H, UrH, nih + ro * NBR, nio + ro * NBR, lbl + ro,
            Wr_w, Wr_b, Ur_b, sumh, gated, curO + ro * 256);
        gemm2_nt<<<dim3(EE / 64, 4, 2), 256, 0, stream>>>(
            sumh, Wz_w, zpre, gated, Wh_w, ppre);
        combine_ur_gemm<<<dim3(EE / 64, 4), 256, 0, stream>>>(
            zpre, ppre, sumh, lbl + ro, Wz_w, Wz_b, Wh_w, Wh_b, Ur_w,
            H + 256 + ro * 256, UrH + 256 + ro * 256);
    }

    root_o_kernel<<<BB, 256, 0, stream>>>(H, rni, curO + (size_t)TE * 256);

    // ---- stop head ----
    // pre1 = curO @ Ui_w[:, 6:].T  -> UrH  (UrH dead after scan)
    gemm_nt<<<dim3((NROWS + 63) / 64, 4), 256, 0, stream>>>(curO, NROWS, Ui_w, 262, VV, UrH);
    // pre2 = relu(pre1 + Ui_col + Ui_b) @ U_w[:, :256].T -> curO (fused)
    relu_gemm<<<dim3((NROWS + 63) / 64, 4), 256, 0, stream>>>(
        UrH, lbl, rlb, Ui_w, Ui_b, U_w, curO);
    stop_head<<<NROWS, 256, 0, stream>>>(curO, latW2, U_b, Uo_w, Uo_b, ctx, dir, part2);

    // ---- pred head (UrH free again) ----
    gemm_nt_v<<<dim3(TE / 64, 4), 256, 0, stream>>>(H + 256, TE, W_w, 384, UrH);
    pred_head<<<NROWS, 256, 0, stream>>>(UrH, latW, W_b, Wo_w, Wo_b,
                                         ctx, dir, ptg, rlb, part1);

    reduce_parts<<<256, 256, 0, stream>>>(part1, part2, accum);
    finalize<<<1, 64, 0, stream>>>(accum, (float*)d_out);
}

// Round 9
// 1433.266 us; speedup vs baseline: 1.8462x; 1.8462x over previous
//
#include <hip/hip_runtime.h>
#include <math.h>

// Problem constants
#define HID 256
#define LAT 128
#define BB  32
#define TT  32
#define EE  2048
#define NBR 10
#define VV  6
#define TE  (TT*EE)          // 65536
#define NROWS (TE + BB)      // 65568
#define MROWS (TE + 1)       // 65537

typedef __attribute__((ext_vector_type(8))) short bfrag;   // 8 bf16 (4 VGPRs)
typedef __attribute__((ext_vector_type(4))) float ffrag;   // 4 fp32 acc

__device__ __forceinline__ float sigmoidf_(float x) { return 1.0f / (1.0f + expf(-x)); }

__device__ __forceinline__ float bf2f(unsigned short u) {
    union { unsigned int i; float f; } x; x.i = ((unsigned int)u) << 16; return x.f;
}
__device__ __forceinline__ unsigned short f2bf(float f) {
    union { float f; unsigned int i; } x; x.f = f;
    unsigned int r = x.i + 0x7FFFu + ((x.i >> 16) & 1u);   // RNE
    return (unsigned short)(r >> 16);
}

// ---------------------------------------------------------------------------
// Prep: bf16 weight copies. dst[n][k] = src[n*ldw + koff + k], grid (256, 6).
// ---------------------------------------------------------------------------
__global__ __launch_bounds__(256) void prep_all(
    const float* __restrict__ Wz, const float* __restrict__ Wh,
    const float* __restrict__ Ur, const float* __restrict__ Ui,
    const float* __restrict__ Ww, const float* __restrict__ Uw,
    unsigned short* __restrict__ dWz, unsigned short* __restrict__ dWh,
    unsigned short* __restrict__ dUr, unsigned short* __restrict__ dUi,
    unsigned short* __restrict__ dWw, unsigned short* __restrict__ dUw)
{
    const int n = blockIdx.x, k = threadIdx.x;
    const float* s; unsigned short* d; int ldw, koff;
    switch (blockIdx.y) {
        case 0:  s = Wz; d = dWz; ldw = 262; koff = VV; break;
        case 1:  s = Wh; d = dWh; ldw = 262; koff = VV; break;
        case 2:  s = Ur; d = dUr; ldw = 256; koff = 0;  break;
        case 3:  s = Ui; d = dUi; ldw = 262; koff = VV; break;
        case 4:  s = Ww; d = dWw; ldw = 384; koff = 0;  break;
        default: s = Uw; d = dUw; ldw = 384; koff = 0;  break;
    }
    d[n * 256 + k] = f2bf(s[(size_t)n * ldw + koff + k]);
}

// Label-column tables (one-hot x parts folded with biases). grid (VV), 256 thr.
__global__ __launch_bounds__(256) void prep_cols(
    const float* __restrict__ Wz_w, const float* __restrict__ Wz_b,
    const float* __restrict__ Wh_w, const float* __restrict__ Wh_b,
    const float* __restrict__ Wr_w, const float* __restrict__ Wr_b,
    const float* __restrict__ Ur_b,
    const float* __restrict__ Ui_w, const float* __restrict__ Ui_b,
    float* __restrict__ zcol, float* __restrict__ hcol,
    float* __restrict__ rcol, float* __restrict__ icol)
{
    const int v = blockIdx.x, h = threadIdx.x;
    zcol[v * 256 + h] = Wz_w[h * 262 + v] + Wz_b[h];
    hcol[v * 256 + h] = Wh_w[h * 262 + v] + Wh_b[h];
    rcol[v * 256 + h] = Wr_w[h * VV + v] + Wr_b[h] + Ur_b[h];
    icol[v * 256 + h] = Ui_w[h * 262 + v] + Ui_b[h];
}

// latent @ {W_w,U_w}[:,256:384].T -> latW/latW2 [B][256] fp32
__global__ __launch_bounds__(256) void lat_gemm2(
    const float* __restrict__ lat,
    const float* __restrict__ W0, const float* __restrict__ W1,
    float* __restrict__ out0, float* __restrict__ out1)
{
    const int b = blockIdx.x, h = threadIdx.x;
    const float* W = blockIdx.y ? W1 : W0;
    float* out     = blockIdx.y ? out1 : out0;
    float acc = 0.f;
    #pragma unroll 4
    for (int k = 0; k < LAT; ++k)
        acc += lat[b * LAT + k] * W[h * 384 + 256 + k];
    out[b * 256 + h] = acc;
}

// ---------------------------------------------------------------------------
// Fused scan step: gather -> MFMA z/h GEMMs -> combine (in-register) ->
// MFMA Ur GEMM -> write Hb/Ub rows. 128 blocks x 512 thr, 16 edges/block.
// Gather SKIPS indices in the current step's row range (they read as zero in
// the reference because writes happen after the gathers) -> race-free.
// ---------------------------------------------------------------------------
#define SFP 268   // fp32 LDS row stride (sumh)
#define SHP 280   // bf16 LDS row stride (gated / nh)

__global__ __launch_bounds__(512) void step_fused(
    const unsigned short* __restrict__ Hb,   // [>=MROWS][256] bf16
    const unsigned short* __restrict__ Ub,   // H @ Ur^T, bf16
    const int* __restrict__ nih, const int* __restrict__ nio,  // +t*EE*NBR
    const int* __restrict__ labels,                             // +t*EE
    const float* __restrict__ rcol, const float* __restrict__ zcol,
    const float* __restrict__ hcol,
    const unsigned short* __restrict__ Wzb,
    const unsigned short* __restrict__ Whb,
    const unsigned short* __restrict__ Urb,
    unsigned short* __restrict__ HbW, unsigned short* __restrict__ UbW,
    unsigned short* __restrict__ curOb,      // +t*EE*256
    int rowg_base)                           // 1 + t*EE
{
    __shared__ float          s_sum[16][SFP];
    __shared__ unsigned short s_gat[16][SHP];
    __shared__ unsigned short s_nh [16][SHP];
    __shared__ int s_idxh[16][NBR];
    __shared__ int s_idxo[16][NBR];
    __shared__ int s_lbl[16];

    const int tid = threadIdx.x;
    const int e0  = blockIdx.x * 16;

    if (tid < 160) {
        s_idxh[tid / NBR][tid % NBR] = nih[e0 * NBR + tid];
        s_idxo[tid / NBR][tid % NBR] = nio[e0 * NBR + tid];
    }
    if (tid >= 160 && tid < 176) s_lbl[tid - 160] = labels[e0 + tid - 160];
    __syncthreads();

    const int w = tid >> 6;      // wave 0..7
    const int l = tid & 63;

    // ---------------- gather ----------------
    {
        const int el = w * 2 + (l >> 5);     // local edge 0..15
        const int h0 = (l & 31) * 8;         // 8 hidden dims per lane
        float s[8], g[8], o[8], rc[8];
        #pragma unroll
        for (int j = 0; j < 8; ++j) { s[j] = 0.f; g[j] = 0.f; o[j] = 0.f; }
        const int lb = s_lbl[el];
        #pragma unroll
        for (int j = 0; j < 8; ++j) rc[j] = rcol[lb * 256 + h0 + j];

        #pragma unroll
        for (int nb = 0; nb < NBR; ++nb) {
            const int ih = s_idxh[el][nb];
            if ((unsigned)(ih - rowg_base) >= (unsigned)EE) {
                uint4 hv = *reinterpret_cast<const uint4*>(Hb + (size_t)ih * 256 + h0);
                uint4 uv = *reinterpret_cast<const uint4*>(Ub + (size_t)ih * 256 + h0);
                const unsigned short* hp = reinterpret_cast<const unsigned short*>(&hv);
                const unsigned short* up = reinterpret_cast<const unsigned short*>(&uv);
                #pragma unroll
                for (int j = 0; j < 8; ++j) {
                    const float hf = bf2f(hp[j]);
                    s[j] += hf;
                    g[j] += hf * sigmoidf_(rc[j] + bf2f(up[j]));
                }
            }
            const int io = s_idxo[el][nb];
            if ((unsigned)(io - rowg_base) >= (unsigned)EE) {
                uint4 ov = *reinterpret_cast<const uint4*>(Hb + (size_t)io * 256 + h0);
                const unsigned short* op = reinterpret_cast<const unsigned short*>(&ov);
                #pragma unroll
                for (int j = 0; j < 8; ++j) o[j] += bf2f(op[j]);
            }
        }
        *reinterpret_cast<float4*>(&s_sum[el][h0])     = make_float4(s[0], s[1], s[2], s[3]);
        *reinterpret_cast<float4*>(&s_sum[el][h0 + 4]) = make_float4(s[4], s[5], s[6], s[7]);
        union { unsigned short u[8]; uint4 v; } gu, ou;
        #pragma unroll
        for (int j = 0; j < 8; ++j) { gu.u[j] = f2bf(g[j]); ou.u[j] = f2bf(o[j]); }
        *reinterpret_cast<uint4*>(&s_gat[el][h0]) = gu.v;
        *reinterpret_cast<uint4*>(curOb + (size_t)(e0 + el) * 256 + h0) = ou.v;
    }
    __syncthreads();

    // ---------------- MFMA z & h GEMMs (wave n-slice 32) ----------------
    const int ar  = l & 15;          // A row / B col
    const int kg  = (l >> 4) * 8;    // k sub-offset
    const int nb0 = w * 32;

    ffrag zacc[2], pacc[2];
    #pragma unroll
    for (int nt = 0; nt < 2; ++nt) {
        zacc[nt] = (ffrag){0.f, 0.f, 0.f, 0.f};
        pacc[nt] = (ffrag){0.f, 0.f, 0.f, 0.f};
    }
    #pragma unroll
    for (int ks = 0; ks < 8; ++ks) {
        const int k0 = ks * 32 + kg;
        bfrag az;
        const float* ap = &s_sum[ar][k0];
        #pragma unroll
        for (int j = 0; j < 8; ++j) az[j] = (short)f2bf(ap[j]);
        bfrag ah = *reinterpret_cast<const bfrag*>(&s_gat[ar][k0]);
        #pragma unroll
        for (int nt = 0; nt < 2; ++nt) {
            const int n = nb0 + nt * 16 + ar;
            bfrag bz = *reinterpret_cast<const bfrag*>(Wzb + (size_t)n * 256 + k0);
            bfrag bh = *reinterpret_cast<const bfrag*>(Whb + (size_t)n * 256 + k0);
            zacc[nt] = __builtin_amdgcn_mfma_f32_16x16x32_bf16(az, bz, zacc[nt], 0, 0, 0);
            pacc[nt] = __builtin_amdgcn_mfma_f32_16x16x32_bf16(ah, bh, pacc[nt], 0, 0, 0);
        }
    }

    // ---------------- combine in-register ----------------
    #pragma unroll
    for (int nt = 0; nt < 2; ++nt) {
        const int n = nb0 + nt * 16 + (l & 15);
        #pragma unroll
        for (int r = 0; r < 4; ++r) {
            const int m  = (l >> 4) * 4 + r;
            const int lb = s_lbl[m];
            const float z  = sigmoidf_(zacc[nt][r] + zcol[lb * 256 + n]);
            const float ph = tanhf(pacc[nt][r] + hcol[lb * 256 + n]);
            const float nh = (1.f - z) * s_sum[m][n] + z * ph;
            s_nh[m][n] = f2bf(nh);
        }
    }
    __syncthreads();

    // copy new_h -> Hb rows (coalesced)
    {
        const int row = tid >> 5, c8 = (tid & 31) * 8;
        uint4 v = *reinterpret_cast<const uint4*>(&s_nh[row][c8]);
        *reinterpret_cast<uint4*>(HbW + (size_t)(rowg_base + e0 + row) * 256 + c8) = v;
    }

    // ---------------- MFMA Ur GEMM ----------------
    ffrag uacc[2];
    #pragma unroll
    for (int nt = 0; nt < 2; ++nt) uacc[nt] = (ffrag){0.f, 0.f, 0.f, 0.f};
    #pragma unroll
    for (int ks = 0; ks < 8; ++ks) {
        const int k0 = ks * 32 + kg;
        bfrag a = *reinterpret_cast<const bfrag*>(&s_nh[ar][k0]);
        #pragma unroll
        for (int nt = 0; nt < 2; ++nt) {
            const int n = nb0 + nt * 16 + ar;
            bfrag b = *reinterpret_cast<const bfrag*>(Urb + (size_t)n * 256 + k0);
            uacc[nt] = __builtin_amdgcn_mfma_f32_16x16x32_bf16(a, b, uacc[nt], 0, 0, 0);
        }
    }
    // stage into s_gat (dead after z/h GEMMs; all waves passed combine barrier)
    #pragma unroll
    for (int nt = 0; nt < 2; ++nt) {
        const int n = nb0 + nt * 16 + (l & 15);
        #pragma unroll
        for (int r = 0; r < 4; ++r) {
            const int m = (l >> 4) * 4 + r;
            s_gat[m][n] = f2bf(uacc[nt][r]);
        }
    }
    __syncthreads();
    {
        const int row = tid >> 5, c8 = (tid & 31) * 8;
        uint4 v = *reinterpret_cast<const uint4*>(&s_gat[row][c8]);
        *reinterpret_cast<uint4*>(UbW + (size_t)(rowg_base + e0 + row) * 256 + c8) = v;
    }
}

// ---------------------------------------------------------------------------
// MFMA head GEMM: C[M][256] = A[M][256] @ Wb^T (Wb is [N=256][K=256] bf16).
// Block: 64 rows x 256 cols, 4 waves (n-slice 64 each), K-chunk 32.
// EPI 0: plain bf16 store. EPI 1: v = relu(v + icol[lbl[row]][n]) (stop h1).
// ---------------------------------------------------------------------------
template<int EPI>
__global__ __launch_bounds__(256) void hgemm(
    const unsigned short* __restrict__ A, int M,
    const unsigned short* __restrict__ Wb,
    const int* __restrict__ lab1, const int* __restrict__ lab2,
    const float* __restrict__ icol,
    unsigned short* __restrict__ C)
{
    __shared__ unsigned short sbuf[64 * 264];  // As view [64][40] / Cs view [64][264]
    __shared__ int s_lb[64];

    const int tid = threadIdx.x;
    const int m0  = blockIdx.x * 64;

    if (EPI == 1 && tid < 64) {
        const int r = m0 + tid;
        int lb = 0;
        if (r < M) lb = (r < TE) ? lab1[r] : lab2[r - TE];
        s_lb[tid] = lb;
    }

    const int w  = tid >> 6;
    const int l  = tid & 63;
    const int ar = l & 15;
    const int kg = (l >> 4) * 8;
    const int lrow = tid >> 2;          // A-load row 0..63
    const int lcol = (tid & 3) * 8;     // A-load col seg

    ffrag acc[4][4];
    #pragma unroll
    for (int mt = 0; mt < 4; ++mt)
        #pragma unroll
        for (int nt = 0; nt < 4; ++nt)
            acc[mt][nt] = (ffrag){0.f, 0.f, 0.f, 0.f};

    for (int kc = 0; kc < 8; ++kc) {
        const int k0 = kc * 32;
        uint4 av = make_uint4(0u, 0u, 0u, 0u);
        if (m0 + lrow < M)
            av = *reinterpret_cast<const uint4*>(A + (size_t)(m0 + lrow) * 256 + k0 + lcol);
        if (kc) __syncthreads();
        *reinterpret_cast<uint4*>(&sbuf[lrow * 40 + lcol]) = av;
        __syncthreads();
        bfrag a[4];
        #pragma unroll
        for (int mt = 0; mt < 4; ++mt)
            a[mt] = *reinterpret_cast<const bfrag*>(&sbuf[(mt * 16 + ar) * 40 + kg]);
        #pragma unroll
        for (int nt = 0; nt < 4; ++nt) {
            const int n = w * 64 + nt * 16 + ar;
            bfrag b = *reinterpret_cast<const bfrag*>(Wb + (size_t)n * 256 + k0 + kg);
            #pragma unroll
            for (int mt = 0; mt < 4; ++mt)
                acc[mt][nt] = __builtin_amdgcn_mfma_f32_16x16x32_bf16(a[mt], b, acc[mt][nt], 0, 0, 0);
        }
    }
    __syncthreads();

    // epilogue: stage bf16 C tile
    #pragma unroll
    for (int mt = 0; mt < 4; ++mt) {
        #pragma unroll
        for (int nt = 0; nt < 4; ++nt) {
            const int n = w * 64 + nt * 16 + (l & 15);
            #pragma unroll
            for (int r = 0; r < 4; ++r) {
                const int m = mt * 16 + (l >> 4) * 4 + r;
                float v = acc[mt][nt][r];
                if (EPI == 1) v = fmaxf(v + icol[s_lb[m] * 256 + n], 0.f);
                sbuf[m * 264 + n] = f2bf(v);
            }
        }
    }
    __syncthreads();
    // coalesced copy out
    {
        const int row = tid >> 2;
        const int cb  = (tid & 3) * 64;
        if (m0 + row < M) {
            #pragma unroll
            for (int q = 0; q < 8; ++q) {
                const int col = cb + q * 8;
                uint4 v = *reinterpret_cast<const uint4*>(&sbuf[row * 264 + col]);
                *reinterpret_cast<uint4*>(C + (size_t)(m0 + row) * 256 + col) = v;
            }
        }
    }
}

// ---------------------------------------------------------------------------
// root_o[i] = sum_nb Hb[root_nei_idx[i][nb]]  -> curOb rows TE..TE+B-1 (bf16)
// ---------------------------------------------------------------------------
__global__ __launch_bounds__(256) void root_o_kernel(
    const unsigned short* __restrict__ Hb, const int* __restrict__ rni,
    unsigned short* __restrict__ dst)
{
    const int b = blockIdx.x, h = threadIdx.x;
    float o = 0.f;
    #pragma unroll
    for (int nb = 0; nb < NBR; ++nb)
        o += bf2f(Hb[(size_t)rni[b * NBR + nb] * 256 + h]);
    dst[(size_t)b * 256 + h] = f2bf(o);
}

// ---------------------------------------------------------------------------
// Pred head (reads bf16 pre)
// ---------------------------------------------------------------------------
__global__ __launch_bounds__(256) void pred_head(
    const unsigned short* __restrict__ pre, const float* __restrict__ latW,
    const float* __restrict__ W_b,
    const float* __restrict__ Wo_w, const float* __restrict__ Wo_b,
    const int* __restrict__ contexts, const int* __restrict__ direction,
    const int* __restrict__ ptgt, const int* __restrict__ root_labels,
    float* __restrict__ part)                                  // [NROWS][3]
{
    const int r = blockIdx.x;
    const int h = threadIdx.x;
    int tgt;
    float mask, v;
    if (r < TE) {
        const int c = contexts[r];
        tgt = ptgt[r];
        mask = (direction[r] == 1) ? 1.f : 0.f;
        v = bf2f(pre[(size_t)r * 256 + h]) + latW[c * 256 + h] + W_b[h];
    } else {
        const int i = r - TE;
        tgt = root_labels[i];
        mask = 1.f;
        v = latW[i * 256 + h] + W_b[h];
    }
    v = fmaxf(v, 0.f);

    __shared__ float red[VV][4];
    const int lane = h & 63, wv = h >> 6;
    #pragma unroll
    for (int c = 0; c < VV; ++c) {
        float x = v * Wo_w[c * 256 + h];
        #pragma unroll
        for (int off = 32; off; off >>= 1) x += __shfl_down(x, off);
        if (lane == 0) red[c][wv] = x;
    }
    __syncthreads();
    if (h == 0) {
        float sc[VV];
        #pragma unroll
        for (int c = 0; c < VV; ++c)
            sc[c] = red[c][0] + red[c][1] + red[c][2] + red[c][3] + Wo_b[c];
        float mx = sc[0];
        int am = 0;
        #pragma unroll
        for (int c = 1; c < VV; ++c)
            if (sc[c] > mx) { mx = sc[c]; am = c; }
        float se = 0.f;
        #pragma unroll
        for (int c = 0; c < VV; ++c) se += expf(sc[c] - mx);
        const float lse = mx + logf(se);
        const float ce = lse - sc[tgt];
        part[(size_t)r * 3 + 0] = ce * mask;
        part[(size_t)r * 3 + 1] = mask;
        part[(size_t)r * 3 + 2] = (am == tgt) ? mask : 0.f;
    }
}

// ---------------------------------------------------------------------------
// Stop head final (reads bf16 pre2)
// ---------------------------------------------------------------------------
__global__ __launch_bounds__(256) void stop_head(
    const unsigned short* __restrict__ pre2, const float* __restrict__ latW2,
    const float* __restrict__ U_b,
    const float* __restrict__ Uo_w, const float* __restrict__ Uo_b,
    const int* __restrict__ contexts, const int* __restrict__ direction,
    float* __restrict__ part2)                                 // [NROWS][2]
{
    const int r = blockIdx.x;
    const int h = threadIdx.x;
    const int c = (r < TE) ? contexts[r] : (r - TE);
    const float tgt = (r < TE) ? (float)direction[r] : 0.f;
    float v = fmaxf(bf2f(pre2[(size_t)r * 256 + h]) + latW2[c * 256 + h] + U_b[h], 0.f);
    float x = v * Uo_w[h];
    #pragma unroll
    for (int off = 32; off; off >>= 1) x += __shfl_down(x, off);
    __shared__ float red[4];
    const int lane = h & 63, wv = h >> 6;
    if (lane == 0) red[wv] = x;
    __syncthreads();
    if (h == 0) {
        const float s = red[0] + red[1] + red[2] + red[3] + Uo_b[0];
        const float loss = fmaxf(s, 0.f) - s * tgt + log1pf(expf(-fabsf(s)));
        const float stop = (s >= 0.f) ? 1.f : 0.f;
        part2[(size_t)r * 2 + 0] = loss;
        part2[(size_t)r * 2 + 1] = (stop == tgt) ? 1.f : 0.f;
    }
}

// ---------------------------------------------------------------------------
__global__ __launch_bounds__(256) void reduce_parts(
    const float* __restrict__ p1, const float* __restrict__ p2,
    float* __restrict__ accum)
{
    float a[5] = {0.f, 0.f, 0.f, 0.f, 0.f};
    const int stride = gridDim.x * blockDim.x;
    for (int r = blockIdx.x * blockDim.x + threadIdx.x; r < NROWS; r += stride) {
        a[0] += p1[(size_t)r * 3 + 0];
        a[1] += p1[(size_t)r * 3 + 1];
        a[2] += p1[(size_t)r * 3 + 2];
        a[3] += p2[(size_t)r * 2 + 0];
        a[4] += p2[(size_t)r * 2 + 1];
    }
    __shared__ float red[5][4];
    const int lane = threadIdx.x & 63, wv = threadIdx.x >> 6;
    #pragma unroll
    for (int i = 0; i < 5; ++i) {
        float x = a[i];
        #pragma unroll
        for (int off = 32; off; off >>= 1) x += __shfl_down(x, off);
        if (lane == 0) red[i][wv] = x;
    }
    __syncthreads();
    if (threadIdx.x < 5) {
        const float s = red[threadIdx.x][0] + red[threadIdx.x][1] +
                        red[threadIdx.x][2] + red[threadIdx.x][3];
        atomicAdd(&accum[threadIdx.x], s);
    }
}

__global__ void finalize(const float* __restrict__ accum, float* __restrict__ out)
{
    if (threadIdx.x == 0) {
        out[0] = accum[0] / (float)BB;            // pred_loss
        out[1] = accum[3] / (float)BB;            // stop_loss
        out[2] = accum[2] / accum[1];             // pred_acc
        out[3] = accum[4] / (float)NROWS;         // stop_acc
    }
}

// ---------------------------------------------------------------------------
extern "C" void kernel_launch(void* const* d_in, const int* in_sizes, int n_in,
                              void* d_out, int out_size, void* d_ws, size_t ws_size,
                              hipStream_t stream)
{
    const float* lat  = (const float*)d_in[0];
    const int*   nih  = (const int*)d_in[1];
    const int*   nio  = (const int*)d_in[2];
    const int*   lbl  = (const int*)d_in[3];
    const int*   ctx  = (const int*)d_in[4];
    const int*   dir  = (const int*)d_in[5];
    const int*   ptg  = (const int*)d_in[6];
    const int*   rlb  = (const int*)d_in[7];
    const int*   rni  = (const int*)d_in[8];
    const float* Wz_w = (const float*)d_in[9],  *Wz_b = (const float*)d_in[10];
    const float* Wr_w = (const float*)d_in[11], *Wr_b = (const float*)d_in[12];
    const float* Ur_w = (const float*)d_in[13], *Ur_b = (const float*)d_in[14];
    const float* Wh_w = (const float*)d_in[15], *Wh_b = (const float*)d_in[16];
    const float* W_w  = (const float*)d_in[17], *W_b  = (const float*)d_in[18];
    const float* Wo_w = (const float*)d_in[19], *Wo_b = (const float*)d_in[20];
    const float* U_w  = (const float*)d_in[21], *U_b  = (const float*)d_in[22];
    const float* Uo_w = (const float*)d_in[23], *Uo_b = (const float*)d_in[24];
    const float* Ui_w = (const float*)d_in[25], *Ui_b = (const float*)d_in[26];

    // ---- workspace bump allocator (all sizes 256B-aligned) ----
    char* p = (char*)d_ws;
    auto alloc = [&](size_t bytes) -> void* {
        void* r = (void*)p; p += (bytes + 255) & ~(size_t)255; return r;
    };
    const size_t RB2 = (size_t)NROWS * 256 * sizeof(unsigned short);  // 33.57 MB
    unsigned short* Hb    = (unsigned short*)alloc(RB2);  // message rows (row0 zero)
    unsigned short* Ub    = (unsigned short*)alloc(RB2);  // H @ Ur^T
    unsigned short* curOb = (unsigned short*)alloc(RB2);  // [NROWS][256]
    unsigned short* h1b   = (unsigned short*)alloc(RB2);  // stop h1; later pred pre
    unsigned short* pre2b = (unsigned short*)alloc(RB2);  // stop pre2
    unsigned short* Wzb = (unsigned short*)alloc(65536 * 2);
    unsigned short* Whb = (unsigned short*)alloc(65536 * 2);
    unsigned short* Urb = (unsigned short*)alloc(65536 * 2);
    unsigned short* Uib = (unsigned short*)alloc(65536 * 2);
    unsigned short* Wwb = (unsigned short*)alloc(65536 * 2);
    unsigned short* Uwb = (unsigned short*)alloc(65536 * 2);
    float* zcol  = (float*)alloc(VV * 256 * 4);
    float* hcol  = (float*)alloc(VV * 256 * 4);
    float* rcol  = (float*)alloc(VV * 256 * 4);
    float* icol  = (float*)alloc(VV * 256 * 4);
    float* latW  = (float*)alloc(BB * 256 * 4);
    float* latW2 = (float*)alloc(BB * 256 * 4);
    float* part1 = (float*)alloc((size_t)NROWS * 3 * 4);
    float* part2 = (float*)alloc((size_t)NROWS * 2 * 4);
    float* accum = (float*)alloc(32);
    // total ~171 MB

    // Hb/Ub must read as zero for unwritten rows (ws re-poisoned each launch)
    hipMemsetAsync(Hb, 0, RB2, stream);
    hipMemsetAsync(Ub, 0, RB2, stream);
    hipMemsetAsync(accum, 0, 32, stream);

    prep_all<<<dim3(256, 6), 256, 0, stream>>>(Wz_w, Wh_w, Ur_w, Ui_w, W_w, U_w,
                                               Wzb, Whb, Urb, Uib, Wwb, Uwb);
    prep_cols<<<VV, 256, 0, stream>>>(Wz_w, Wz_b, Wh_w, Wh_b, Wr_w, Wr_b, Ur_b,
                                      Ui_w, Ui_b, zcol, hcol, rcol, icol);
    lat_gemm2<<<dim3(BB, 2), 256, 0, stream>>>(lat, W_w, U_w, latW, latW2);

    for (int t = 0; t < TT; ++t) {
        step_fused<<<EE / 16, 512, 0, stream>>>(
            Hb, Ub, nih + (size_t)t * EE * NBR, nio + (size_t)t * EE * NBR,
            lbl + t * EE, rcol, zcol, hcol, Wzb, Whb, Urb,
            Hb, Ub, curOb + (size_t)t * EE * 256, 1 + t * EE);
    }

    root_o_kernel<<<BB, 256, 0, stream>>>(Hb, rni, curOb + (size_t)TE * 256);

    // ---- stop head ----
    hgemm<1><<<(NROWS + 63) / 64, 256, 0, stream>>>(curOb, NROWS, Uib, lbl, rlb, icol, h1b);
    hgemm<0><<<(NROWS + 63) / 64, 256, 0, stream>>>(h1b, NROWS, Uwb, nullptr, nullptr, nullptr, pre2b);
    stop_head<<<NROWS, 256, 0, stream>>>(pre2b, latW2, U_b, Uo_w, Uo_b, ctx, dir, part2);

    // ---- pred head (h1b reused as pre buffer) ----
    hgemm<0><<<TE / 64, 256, 0, stream>>>(Hb + 256, TE, Wwb, nullptr, nullptr, nullptr, h1b);
    pred_head<<<NROWS, 256, 0, stream>>>(h1b, latW, W_b, Wo_w, Wo_b,
                                         ctx, dir, ptg, rlb, part1);

    reduce_parts<<<256, 256, 0, stream>>>(part1, part2, accum);
    finalize<<<1, 64, 0, stream>>>(accum, (float*)d_out);
}

// Round 10
// 1316.356 us; speedup vs baseline: 2.0101x; 1.0888x over previous
//
#include <hip/hip_runtime.h>
#include <math.h>

// Problem constants
#define HID 256
#define LAT 128
#define BB  32
#define TT  32
#define EE  2048
#define NBR 10
#define VV  6
#define TE  (TT*EE)          // 65536
#define NROWS (TE + BB)      // 65568
#define MROWS (TE + 1)       // 65537

typedef __attribute__((ext_vector_type(8))) short bfrag;   // 8 bf16 (4 VGPRs)
typedef __attribute__((ext_vector_type(4))) float ffrag;   // 4 fp32 acc

__device__ __forceinline__ float sigmoidf_(float x) { return 1.0f / (1.0f + expf(-x)); }

__device__ __forceinline__ float bf2f(unsigned short u) {
    union { unsigned int i; float f; } x; x.i = ((unsigned int)u) << 16; return x.f;
}
__device__ __forceinline__ unsigned short f2bf(float f) {
    union { float f; unsigned int i; } x; x.f = f;
    unsigned int r = x.i + 0x7FFFu + ((x.i >> 16) & 1u);   // RNE
    return (unsigned short)(r >> 16);
}

// ---------------------------------------------------------------------------
// Prep: bf16 weight copies. dst[n][k] = src[n*ldw + koff + k], grid (256, 6).
// ---------------------------------------------------------------------------
__global__ __launch_bounds__(256) void prep_all(
    const float* __restrict__ Wz, const float* __restrict__ Wh,
    const float* __restrict__ Ur, const float* __restrict__ Ui,
    const float* __restrict__ Ww, const float* __restrict__ Uw,
    unsigned short* __restrict__ dWz, unsigned short* __restrict__ dWh,
    unsigned short* __restrict__ dUr, unsigned short* __restrict__ dUi,
    unsigned short* __restrict__ dWw, unsigned short* __restrict__ dUw)
{
    const int n = blockIdx.x, k = threadIdx.x;
    const float* s; unsigned short* d; int ldw, koff;
    switch (blockIdx.y) {
        case 0:  s = Wz; d = dWz; ldw = 262; koff = VV; break;
        case 1:  s = Wh; d = dWh; ldw = 262; koff = VV; break;
        case 2:  s = Ur; d = dUr; ldw = 256; koff = 0;  break;
        case 3:  s = Ui; d = dUi; ldw = 262; koff = VV; break;
        case 4:  s = Ww; d = dWw; ldw = 384; koff = 0;  break;
        default: s = Uw; d = dUw; ldw = 384; koff = 0;  break;
    }
    d[n * 256 + k] = f2bf(s[(size_t)n * ldw + koff + k]);
}

// Label-column tables (one-hot x parts folded with biases). grid (VV), 256 thr.
__global__ __launch_bounds__(256) void prep_cols(
    const float* __restrict__ Wz_w, const float* __restrict__ Wz_b,
    const float* __restrict__ Wh_w, const float* __restrict__ Wh_b,
    const float* __restrict__ Wr_w, const float* __restrict__ Wr_b,
    const float* __restrict__ Ur_b,
    const float* __restrict__ Ui_w, const float* __restrict__ Ui_b,
    float* __restrict__ zcol, float* __restrict__ hcol,
    float* __restrict__ rcol, float* __restrict__ icol)
{
    const int v = blockIdx.x, h = threadIdx.x;
    zcol[v * 256 + h] = Wz_w[h * 262 + v] + Wz_b[h];
    hcol[v * 256 + h] = Wh_w[h * 262 + v] + Wh_b[h];
    rcol[v * 256 + h] = Wr_w[h * VV + v] + Wr_b[h] + Ur_b[h];
    icol[v * 256 + h] = Ui_w[h * 262 + v] + Ui_b[h];
}

// latent @ {W_w,U_w}[:,256:384].T -> latW/latW2 [B][256] fp32
__global__ __launch_bounds__(256) void lat_gemm2(
    const float* __restrict__ lat,
    const float* __restrict__ W0, const float* __restrict__ W1,
    float* __restrict__ out0, float* __restrict__ out1)
{
    const int b = blockIdx.x, h = threadIdx.x;
    const float* W = blockIdx.y ? W1 : W0;
    float* out     = blockIdx.y ? out1 : out0;
    float acc = 0.f;
    #pragma unroll 4
    for (int k = 0; k < LAT; ++k)
        acc += lat[b * LAT + k] * W[h * 384 + 256 + k];
    out[b * 256 + h] = acc;
}

// ---------------------------------------------------------------------------
// Fused scan step: gather -> MFMA z/h GEMMs -> combine -> MFMA Ur GEMM ->
// write Hb/Ub rows. 256 blocks x 256 thr (4 waves), 8 edges/block.
// MFMA M=16 tiles: rows 8..15 zeroed, outputs for m>=8 ignored.
// Gather SKIPS indices in the current step's row range (they read as zero in
// the reference because writes happen after the gathers) -> race-free.
// ---------------------------------------------------------------------------
#define SFP 268   // fp32 LDS row stride (sumh)
#define SHP 280   // bf16 LDS row stride (gated / nh)

__global__ __launch_bounds__(256) void step_fused(
    const unsigned short* __restrict__ Hb,   // [>=MROWS][256] bf16
    const unsigned short* __restrict__ Ub,   // H @ Ur^T, bf16
    const int* __restrict__ nih, const int* __restrict__ nio,  // +t*EE*NBR
    const int* __restrict__ labels,                             // +t*EE
    const float* __restrict__ rcol, const float* __restrict__ zcol,
    const float* __restrict__ hcol,
    const unsigned short* __restrict__ Wzb,
    const unsigned short* __restrict__ Whb,
    const unsigned short* __restrict__ Urb,
    unsigned short* __restrict__ HbW, unsigned short* __restrict__ UbW,
    unsigned short* __restrict__ curOb,      // +t*EE*256
    int rowg_base)                           // 1 + t*EE
{
    __shared__ float          s_sum[16][SFP];
    __shared__ unsigned short s_gat[16][SHP];
    __shared__ unsigned short s_nh [16][SHP];
    __shared__ int s_idxh[8][NBR];
    __shared__ int s_idxo[8][NBR];
    __shared__ int s_lbl[16];

    const int tid = threadIdx.x;     // 0..255
    const int e0  = blockIdx.x * 8;

    if (tid < 80) {
        s_idxh[tid / NBR][tid % NBR] = nih[e0 * NBR + tid];
    } else if (tid < 160) {
        const int t = tid - 80;
        s_idxo[t / NBR][t % NBR] = nio[e0 * NBR + t];
    } else if (tid < 176) {
        const int t = tid - 160;
        s_lbl[t] = (t < 8) ? labels[e0 + t] : 0;
    }
    // zero MFMA rows 8..15 of s_sum / s_gat / s_nh
    {
        const int zr = 8 + (tid >> 5), zd = (tid & 31) * 8;
        *reinterpret_cast<float4*>(&s_sum[zr][zd])     = make_float4(0.f, 0.f, 0.f, 0.f);
        *reinterpret_cast<float4*>(&s_sum[zr][zd + 4]) = make_float4(0.f, 0.f, 0.f, 0.f);
        const uint4 z4 = make_uint4(0u, 0u, 0u, 0u);
        *reinterpret_cast<uint4*>(&s_gat[zr][zd]) = z4;
        *reinterpret_cast<uint4*>(&s_nh [zr][zd]) = z4;
    }
    __syncthreads();

    const int w = tid >> 6;      // wave 0..3
    const int l = tid & 63;

    // ---------------- gather (one thread per (edge, 8 dims)) ----------------
    {
        const int el = tid >> 5;             // local edge 0..7
        const int h0 = (tid & 31) * 8;       // 8 hidden dims
        float s[8], g[8], o[8], rc[8];
        #pragma unroll
        for (int j = 0; j < 8; ++j) { s[j] = 0.f; g[j] = 0.f; o[j] = 0.f; }
        const int lb = s_lbl[el];
        #pragma unroll
        for (int j = 0; j < 8; ++j) rc[j] = rcol[lb * 256 + h0 + j];

        #pragma unroll
        for (int nb = 0; nb < NBR; ++nb) {
            const int ih = s_idxh[el][nb];
            if ((unsigned)(ih - rowg_base) >= (unsigned)EE) {
                uint4 hv = *reinterpret_cast<const uint4*>(Hb + (size_t)ih * 256 + h0);
                uint4 uv = *reinterpret_cast<const uint4*>(Ub + (size_t)ih * 256 + h0);
                const unsigned short* hp = reinterpret_cast<const unsigned short*>(&hv);
                const unsigned short* up = reinterpret_cast<const unsigned short*>(&uv);
                #pragma unroll
                for (int j = 0; j < 8; ++j) {
                    const float hf = bf2f(hp[j]);
                    s[j] += hf;
                    g[j] += hf * sigmoidf_(rc[j] + bf2f(up[j]));
                }
            }
            const int io = s_idxo[el][nb];
            if ((unsigned)(io - rowg_base) >= (unsigned)EE) {
                uint4 ov = *reinterpret_cast<const uint4*>(Hb + (size_t)io * 256 + h0);
                const unsigned short* op = reinterpret_cast<const unsigned short*>(&ov);
                #pragma unroll
                for (int j = 0; j < 8; ++j) o[j] += bf2f(op[j]);
            }
        }
        *reinterpret_cast<float4*>(&s_sum[el][h0])     = make_float4(s[0], s[1], s[2], s[3]);
        *reinterpret_cast<float4*>(&s_sum[el][h0 + 4]) = make_float4(s[4], s[5], s[6], s[7]);
        union { unsigned short u[8]; uint4 v; } gu, ou;
        #pragma unroll
        for (int j = 0; j < 8; ++j) { gu.u[j] = f2bf(g[j]); ou.u[j] = f2bf(o[j]); }
        *reinterpret_cast<uint4*>(&s_gat[el][h0]) = gu.v;
        *reinterpret_cast<uint4*>(curOb + (size_t)(e0 + el) * 256 + h0) = ou.v;
    }
    __syncthreads();

    // ---------------- MFMA z & h GEMMs (wave n-slice 64) ----------------
    const int ar  = l & 15;          // A row / B col
    const int kg  = (l >> 4) * 8;    // k sub-offset
    const int nb0 = w * 64;

    ffrag zacc[4], pacc[4];
    #pragma unroll
    for (int nt = 0; nt < 4; ++nt) {
        zacc[nt] = (ffrag){0.f, 0.f, 0.f, 0.f};
        pacc[nt] = (ffrag){0.f, 0.f, 0.f, 0.f};
    }
    #pragma unroll
    for (int ks = 0; ks < 8; ++ks) {
        const int k0 = ks * 32 + kg;
        bfrag az;
        const float* ap = &s_sum[ar][k0];
        #pragma unroll
        for (int j = 0; j < 8; ++j) az[j] = (short)f2bf(ap[j]);
        bfrag ah = *reinterpret_cast<const bfrag*>(&s_gat[ar][k0]);
        #pragma unroll
        for (int nt = 0; nt < 4; ++nt) {
            const int n = nb0 + nt * 16 + ar;
            bfrag bz = *reinterpret_cast<const bfrag*>(Wzb + (size_t)n * 256 + k0);
            bfrag bh = *reinterpret_cast<const bfrag*>(Whb + (size_t)n * 256 + k0);
            zacc[nt] = __builtin_amdgcn_mfma_f32_16x16x32_bf16(az, bz, zacc[nt], 0, 0, 0);
            pacc[nt] = __builtin_amdgcn_mfma_f32_16x16x32_bf16(ah, bh, pacc[nt], 0, 0, 0);
        }
    }

    // ---------------- combine in-register (valid rows m<8) ----------------
    #pragma unroll
    for (int nt = 0; nt < 4; ++nt) {
        const int n = nb0 + nt * 16 + (l & 15);
        #pragma unroll
        for (int r = 0; r < 4; ++r) {
            const int m = (l >> 4) * 4 + r;
            if (m < 8) {
                const int lb = s_lbl[m];
                const float z  = sigmoidf_(zacc[nt][r] + zcol[lb * 256 + n]);
                const float ph = tanhf(pacc[nt][r] + hcol[lb * 256 + n]);
                const float nh = (1.f - z) * s_sum[m][n] + z * ph;
                s_nh[m][n] = f2bf(nh);
            }
        }
    }
    __syncthreads();

    // copy new_h -> Hb rows (coalesced, 8 rows)
    {
        const int row = tid >> 5, c8 = (tid & 31) * 8;
        uint4 v = *reinterpret_cast<const uint4*>(&s_nh[row][c8]);
        *reinterpret_cast<uint4*>(HbW + (size_t)(rowg_base + e0 + row) * 256 + c8) = v;
    }

    // ---------------- MFMA Ur GEMM ----------------
    ffrag uacc[4];
    #pragma unroll
    for (int nt = 0; nt < 4; ++nt) uacc[nt] = (ffrag){0.f, 0.f, 0.f, 0.f};
    #pragma unroll
    for (int ks = 0; ks < 8; ++ks) {
        const int k0 = ks * 32 + kg;
        bfrag a = *reinterpret_cast<const bfrag*>(&s_nh[ar][k0]);
        #pragma unroll
        for (int nt = 0; nt < 4; ++nt) {
            const int n = nb0 + nt * 16 + ar;
            bfrag b = *reinterpret_cast<const bfrag*>(Urb + (size_t)n * 256 + k0);
            uacc[nt] = __builtin_amdgcn_mfma_f32_16x16x32_bf16(a, b, uacc[nt], 0, 0, 0);
        }
    }
    // stage into s_gat (dead after z/h GEMMs; all waves passed combine barrier)
    #pragma unroll
    for (int nt = 0; nt < 4; ++nt) {
        const int n = nb0 + nt * 16 + (l & 15);
        #pragma unroll
        for (int r = 0; r < 4; ++r) {
            const int m = (l >> 4) * 4 + r;
            if (m < 8) s_gat[m][n] = f2bf(uacc[nt][r]);
        }
    }
    __syncthreads();
    {
        const int row = tid >> 5, c8 = (tid & 31) * 8;
        uint4 v = *reinterpret_cast<const uint4*>(&s_gat[row][c8]);
        *reinterpret_cast<uint4*>(UbW + (size_t)(rowg_base + e0 + row) * 256 + c8) = v;
    }
}

// ---------------------------------------------------------------------------
// MFMA head GEMM: C[M][256] = A[M][256] @ Wb^T (Wb is [N=256][K=256] bf16).
// Block: 64 rows x 256 cols, 4 waves (n-slice 64 each), K-chunk 32.
// EPI 0: plain bf16 store. EPI 1: v = relu(v + icol[lbl[row]][n]) (stop h1).
// ---------------------------------------------------------------------------
template<int EPI>
__global__ __launch_bounds__(256) void hgemm(
    const unsigned short* __restrict__ A, int M,
    const unsigned short* __restrict__ Wb,
    const int* __restrict__ lab1, const int* __restrict__ lab2,
    const float* __restrict__ icol,
    unsigned short* __restrict__ C)
{
    __shared__ unsigned short sbuf[64 * 264];  // As view [64][40] / Cs view [64][264]
    __shared__ int s_lb[64];

    const int tid = threadIdx.x;
    const int m0  = blockIdx.x * 64;

    if (EPI == 1 && tid < 64) {
        const int r = m0 + tid;
        int lb = 0;
        if (r < M) lb = (r < TE) ? lab1[r] : lab2[r - TE];
        s_lb[tid] = lb;
    }

    const int w  = tid >> 6;
    const int l  = tid & 63;
    const int ar = l & 15;
    const int kg = (l >> 4) * 8;
    const int lrow = tid >> 2;          // A-load row 0..63
    const int lcol = (tid & 3) * 8;     // A-load col seg

    ffrag acc[4][4];
    #pragma unroll
    for (int mt = 0; mt < 4; ++mt)
        #pragma unroll
        for (int nt = 0; nt < 4; ++nt)
            acc[mt][nt] = (ffrag){0.f, 0.f, 0.f, 0.f};

    for (int kc = 0; kc < 8; ++kc) {
        const int k0 = kc * 32;
        uint4 av = make_uint4(0u, 0u, 0u, 0u);
        if (m0 + lrow < M)
            av = *reinterpret_cast<const uint4*>(A + (size_t)(m0 + lrow) * 256 + k0 + lcol);
        if (kc) __syncthreads();
        *reinterpret_cast<uint4*>(&sbuf[lrow * 40 + lcol]) = av;
        __syncthreads();
        bfrag a[4];
        #pragma unroll
        for (int mt = 0; mt < 4; ++mt)
            a[mt] = *reinterpret_cast<const bfrag*>(&sbuf[(mt * 16 + ar) * 40 + kg]);
        #pragma unroll
        for (int nt = 0; nt < 4; ++nt) {
            const int n = w * 64 + nt * 16 + ar;
            bfrag b = *reinterpret_cast<const bfrag*>(Wb + (size_t)n * 256 + k0 + kg);
            #pragma unroll
            for (int mt = 0; mt < 4; ++mt)
                acc[mt][nt] = __builtin_amdgcn_mfma_f32_16x16x32_bf16(a[mt], b, acc[mt][nt], 0, 0, 0);
        }
    }
    __syncthreads();

    // epilogue: stage bf16 C tile
    #pragma unroll
    for (int mt = 0; mt < 4; ++mt) {
        #pragma unroll
        for (int nt = 0; nt < 4; ++nt) {
            const int n = w * 64 + nt * 16 + (l & 15);
            #pragma unroll
            for (int r = 0; r < 4; ++r) {
                const int m = mt * 16 + (l >> 4) * 4 + r;
                float v = acc[mt][nt][r];
                if (EPI == 1) v = fmaxf(v + icol[s_lb[m] * 256 + n], 0.f);
                sbuf[m * 264 + n] = f2bf(v);
            }
        }
    }
    __syncthreads();
    // coalesced copy out
    {
        const int row = tid >> 2;
        const int cb  = (tid & 3) * 64;
        if (m0 + row < M) {
            #pragma unroll
            for (int q = 0; q < 8; ++q) {
                const int col = cb + q * 8;
                uint4 v = *reinterpret_cast<const uint4*>(&sbuf[row * 264 + col]);
                *reinterpret_cast<uint4*>(C + (size_t)(m0 + row) * 256 + col) = v;
            }
        }
    }
}

// ---------------------------------------------------------------------------
// root_o[i] = sum_nb Hb[root_nei_idx[i][nb]]  -> curOb rows TE..TE+B-1 (bf16)
// ---------------------------------------------------------------------------
__global__ __launch_bounds__(256) void root_o_kernel(
    const unsigned short* __restrict__ Hb, const int* __restrict__ rni,
    unsigned short* __restrict__ dst)
{
    const int b = blockIdx.x, h = threadIdx.x;
    float o = 0.f;
    #pragma unroll
    for (int nb = 0; nb < NBR; ++nb)
        o += bf2f(Hb[(size_t)rni[b * NBR + nb] * 256 + h]);
    dst[(size_t)b * 256 + h] = f2bf(o);
}

// ---------------------------------------------------------------------------
// Pred head, row-per-lane: one wave per 64 rows. Phase A stages
// relu(pre + latW[ctx] + W_b) as bf16 in LDS (coalesced); phase B: each lane
// owns a row, computes 6 scores in-register (no shuffles), CE/argmax, store.
// ---------------------------------------------------------------------------
__global__ __launch_bounds__(64) void pred_head(
    const unsigned short* __restrict__ pre, const float* __restrict__ latW,
    const float* __restrict__ W_b,
    const float* __restrict__ Wo_w, const float* __restrict__ Wo_b,
    const int* __restrict__ contexts, const int* __restrict__ direction,
    const int* __restrict__ ptgt, const int* __restrict__ root_labels,
    float* __restrict__ part)                                  // [NROWS][3]
{
    __shared__ unsigned short sv[64][264];
    const int l  = threadIdx.x;
    const int r0 = blockIdx.x * 64;

    // Phase A: 32 iterations, each covers 2 rows x 32 lanes x 8 dims.
    for (int it = 0; it < 32; ++it) {
        const int rr  = it * 2 + (l >> 5);
        const int row = r0 + rr;
        const int d0  = (l & 31) * 8;
        float v[8];
        if (row < NROWS) {
            const int c = (row < TE) ? contexts[row] : (row - TE);
            uint4 pv = make_uint4(0u, 0u, 0u, 0u);
            if (row < TE)
                pv = *reinterpret_cast<const uint4*>(pre + (size_t)row * 256 + d0);
            const unsigned short* pp = reinterpret_cast<const unsigned short*>(&pv);
            const float4 la = *reinterpret_cast<const float4*>(latW + c * 256 + d0);
            const float4 lb = *reinterpret_cast<const float4*>(latW + c * 256 + d0 + 4);
            const float4 ba = *reinterpret_cast<const float4*>(W_b + d0);
            const float4 bb = *reinterpret_cast<const float4*>(W_b + d0 + 4);
            const float lv[8] = {la.x, la.y, la.z, la.w, lb.x, lb.y, lb.z, lb.w};
            const float bv[8] = {ba.x, ba.y, ba.z, ba.w, bb.x, bb.y, bb.z, bb.w};
            #pragma unroll
            for (int j = 0; j < 8; ++j) {
                float x = lv[j] + bv[j];
                if (row < TE) x += bf2f(pp[j]);
                v[j] = fmaxf(x, 0.f);
            }
        } else {
            #pragma unroll
            for (int j = 0; j < 8; ++j) v[j] = 0.f;
        }
        union { unsigned short u[8]; uint4 q; } uu;
        #pragma unroll
        for (int j = 0; j < 8; ++j) uu.u[j] = f2bf(v[j]);
        *reinterpret_cast<uint4*>(&sv[rr][d0]) = uu.q;
    }
    __syncthreads();

    // Phase B: lane l owns row r0+l.
    const int row = r0 + l;
    if (row >= NROWS) return;
    float sc[VV];
    #pragma unroll
    for (int c = 0; c < VV; ++c) sc[c] = Wo_b[c];
    for (int it = 0; it < 32; ++it) {
        const int d0 = it * 8;
        bfrag vv = *reinterpret_cast<const bfrag*>(&sv[l][d0]);
        #pragma unroll
        for (int j = 0; j < 8; ++j) {
            const float x = bf2f((unsigned short)vv[j]);
            #pragma unroll
            for (int c = 0; c < VV; ++c)
                sc[c] += x * Wo_w[c * 256 + d0 + j];
        }
    }
    int tgt; float mask;
    if (row < TE) {
        tgt  = ptgt[row];
        mask = (direction[row] == 1) ? 1.f : 0.f;
    } else {
        tgt  = root_labels[row - TE];
        mask = 1.f;
    }
    float mx = sc[0]; int am = 0;
    #pragma unroll
    for (int c = 1; c < VV; ++c)
        if (sc[c] > mx) { mx = sc[c]; am = c; }
    float se = 0.f;
    #pragma unroll
    for (int c = 0; c < VV; ++c) se += expf(sc[c] - mx);
    const float lse = mx + logf(se);
    const float ce = lse - sc[tgt];
    part[(size_t)row * 3 + 0] = ce * mask;
    part[(size_t)row * 3 + 1] = mask;
    part[(size_t)row * 3 + 2] = (am == tgt) ? mask : 0.f;
}

// ---------------------------------------------------------------------------
// Stop head, row-per-lane (same structure, single output).
// ---------------------------------------------------------------------------
__global__ __launch_bounds__(64) void stop_head(
    const unsigned short* __restrict__ pre2, const float* __restrict__ latW2,
    const float* __restrict__ U_b,
    const float* __restrict__ Uo_w, const float* __restrict__ Uo_b,
    const int* __restrict__ contexts, const int* __restrict__ direction,
    float* __restrict__ part2)                                 // [NROWS][2]
{
    __shared__ unsigned short sv[64][264];
    const int l  = threadIdx.x;
    const int r0 = blockIdx.x * 64;

    for (int it = 0; it < 32; ++it) {
        const int rr  = it * 2 + (l >> 5);
        const int row = r0 + rr;
        const int d0  = (l & 31) * 8;
        float v[8];
        if (row < NROWS) {
            const int c = (row < TE) ? contexts[row] : (row - TE);
            uint4 pv = *reinterpret_cast<const uint4*>(pre2 + (size_t)row * 256 + d0);
            const unsigned short* pp = reinterpret_cast<const unsigned short*>(&pv);
            const float4 la = *reinterpret_cast<const float4*>(latW2 + c * 256 + d0);
            const float4 lb = *reinterpret_cast<const float4*>(latW2 + c * 256 + d0 + 4);
            const float4 ba = *reinterpret_cast<const float4*>(U_b + d0);
            const float4 bb = *reinterpret_cast<const float4*>(U_b + d0 + 4);
            const float lv[8] = {la.x, la.y, la.z, la.w, lb.x, lb.y, lb.z, lb.w};
            const float bv[8] = {ba.x, ba.y, ba.z, ba.w, bb.x, bb.y, bb.z, bb.w};
            #pragma unroll
            for (int j = 0; j < 8; ++j)
                v[j] = fmaxf(bf2f(pp[j]) + lv[j] + bv[j], 0.f);
        } else {
            #pragma unroll
            for (int j = 0; j < 8; ++j) v[j] = 0.f;
        }
        union { unsigned short u[8]; uint4 q; } uu;
        #pragma unroll
        for (int j = 0; j < 8; ++j) uu.u[j] = f2bf(v[j]);
        *reinterpret_cast<uint4*>(&sv[rr][d0]) = uu.q;
    }
    __syncthreads();

    const int row = r0 + l;
    if (row >= NROWS) return;
    float s = Uo_b[0];
    for (int it = 0; it < 32; ++it) {
        const int d0 = it * 8;
        bfrag vv = *reinterpret_cast<const bfrag*>(&sv[l][d0]);
        #pragma unroll
        for (int j = 0; j < 8; ++j)
            s += bf2f((unsigned short)vv[j]) * Uo_w[d0 + j];
    }
    const float tgt = (row < TE) ? (float)direction[row] : 0.f;
    const float loss = fmaxf(s, 0.f) - s * tgt + log1pf(expf(-fabsf(s)));
    const float stop = (s >= 0.f) ? 1.f : 0.f;
    part2[(size_t)row * 2 + 0] = loss;
    part2[(size_t)row * 2 + 1] = (stop == tgt) ? 1.f : 0.f;
}

// ---------------------------------------------------------------------------
__global__ __launch_bounds__(256) void reduce_parts(
    const float* __restrict__ p1, const float* __restrict__ p2,
    float* __restrict__ accum)
{
    float a[5] = {0.f, 0.f, 0.f, 0.f, 0.f};
    const int stride = gridDim.x * blockDim.x;
    for (int r = blockIdx.x * blockDim.x + threadIdx.x; r < NROWS; r += stride) {
        a[0] += p1[(size_t)r * 3 + 0];
        a[1] += p1[(size_t)r * 3 + 1];
        a[2] += p1[(size_t)r * 3 + 2];
        a[3] += p2[(size_t)r * 2 + 0];
        a[4] += p2[(size_t)r * 2 + 1];
    }
    __shared__ float red[5][4];
    const int lane = threadIdx.x & 63, wv = threadIdx.x >> 6;
    #pragma unroll
    for (int i = 0; i < 5; ++i) {
        float x = a[i];
        #pragma unroll
        for (int off = 32; off; off >>= 1) x += __shfl_down(x, off);
        if (lane == 0) red[i][wv] = x;
    }
    __syncthreads();
    if (threadIdx.x < 5) {
        const float s = red[threadIdx.x][0] + red[threadIdx.x][1] +
                        red[threadIdx.x][2] + red[threadIdx.x][3];
        atomicAdd(&accum[threadIdx.x], s);
    }
}

__global__ void finalize(const float* __restrict__ accum, float* __restrict__ out)
{
    if (threadIdx.x == 0) {
        out[0] = accum[0] / (float)BB;            // pred_loss
        out[1] = accum[3] / (float)BB;            // stop_loss
        out[2] = accum[2] / accum[1];             // pred_acc
        out[3] = accum[4] / (float)NROWS;         // stop_acc
    }
}

// ---------------------------------------------------------------------------
extern "C" void kernel_launch(void* const* d_in, const int* in_sizes, int n_in,
                              void* d_out, int out_size, void* d_ws, size_t ws_size,
                              hipStream_t stream)
{
    const float* lat  = (const float*)d_in[0];
    const int*   nih  = (const int*)d_in[1];
    const int*   nio  = (const int*)d_in[2];
    const int*   lbl  = (const int*)d_in[3];
    const int*   ctx  = (const int*)d_in[4];
    const int*   dir  = (const int*)d_in[5];
    const int*   ptg  = (const int*)d_in[6];
    const int*   rlb  = (const int*)d_in[7];
    const int*   rni  = (const int*)d_in[8];
    const float* Wz_w = (const float*)d_in[9],  *Wz_b = (const float*)d_in[10];
    const float* Wr_w = (const float*)d_in[11], *Wr_b = (const float*)d_in[12];
    const float* Ur_w = (const float*)d_in[13], *Ur_b = (const float*)d_in[14];
    const float* Wh_w = (const float*)d_in[15], *Wh_b = (const float*)d_in[16];
    const float* W_w  = (const float*)d_in[17], *W_b  = (const float*)d_in[18];
    const float* Wo_w = (const float*)d_in[19], *Wo_b = (const float*)d_in[20];
    const float* U_w  = (const float*)d_in[21], *U_b  = (const float*)d_in[22];
    const float* Uo_w = (const float*)d_in[23], *Uo_b = (const float*)d_in[24];
    const float* Ui_w = (const float*)d_in[25], *Ui_b = (const float*)d_in[26];

    // ---- workspace bump allocator (all sizes 256B-aligned) ----
    char* p = (char*)d_ws;
    auto alloc = [&](size_t bytes) -> void* {
        void* r = (void*)p; p += (bytes + 255) & ~(size_t)255; return r;
    };
    const size_t RB2 = (size_t)NROWS * 256 * sizeof(unsigned short);  // 33.57 MB
    unsigned short* Hb    = (unsigned short*)alloc(RB2);  // message rows (row0 zero)
    unsigned short* Ub    = (unsigned short*)alloc(RB2);  // H @ Ur^T
    unsigned short* curOb = (unsigned short*)alloc(RB2);  // [NROWS][256]
    unsigned short* h1b   = (unsigned short*)alloc(RB2);  // stop h1; later pred pre
    unsigned short* pre2b = (unsigned short*)alloc(RB2);  // stop pre2
    unsigned short* Wzb = (unsigned short*)alloc(65536 * 2);
    unsigned short* Whb = (unsigned short*)alloc(65536 * 2);
    unsigned short* Urb = (unsigned short*)alloc(65536 * 2);
    unsigned short* Uib = (unsigned short*)alloc(65536 * 2);
    unsigned short* Wwb = (unsigned short*)alloc(65536 * 2);
    unsigned short* Uwb = (unsigned short*)alloc(65536 * 2);
    float* zcol  = (float*)alloc(VV * 256 * 4);
    float* hcol  = (float*)alloc(VV * 256 * 4);
    float* rcol  = (float*)alloc(VV * 256 * 4);
    float* icol  = (float*)alloc(VV * 256 * 4);
    float* latW  = (float*)alloc(BB * 256 * 4);
    float* latW2 = (float*)alloc(BB * 256 * 4);
    float* part1 = (float*)alloc((size_t)NROWS * 3 * 4);
    float* part2 = (float*)alloc((size_t)NROWS * 2 * 4);
    float* accum = (float*)alloc(32);
    // total ~171 MB

    // Hb/Ub must read as zero for unwritten rows (ws re-poisoned each launch)
    hipMemsetAsync(Hb, 0, RB2, stream);
    hipMemsetAsync(Ub, 0, RB2, stream);
    hipMemsetAsync(accum, 0, 32, stream);

    prep_all<<<dim3(256, 6), 256, 0, stream>>>(Wz_w, Wh_w, Ur_w, Ui_w, W_w, U_w,
                                               Wzb, Whb, Urb, Uib, Wwb, Uwb);
    prep_cols<<<VV, 256, 0, stream>>>(Wz_w, Wz_b, Wh_w, Wh_b, Wr_w, Wr_b, Ur_b,
                                      Ui_w, Ui_b, zcol, hcol, rcol, icol);
    lat_gemm2<<<dim3(BB, 2), 256, 0, stream>>>(lat, W_w, U_w, latW, latW2);

    for (int t = 0; t < TT; ++t) {
        step_fused<<<EE / 8, 256, 0, stream>>>(
            Hb, Ub, nih + (size_t)t * EE * NBR, nio + (size_t)t * EE * NBR,
            lbl + t * EE, rcol, zcol, hcol, Wzb, Whb, Urb,
            Hb, Ub, curOb + (size_t)t * EE * 256, 1 + t * EE);
    }

    root_o_kernel<<<BB, 256, 0, stream>>>(Hb, rni, curOb + (size_t)TE * 256);

    // ---- stop head ----
    hgemm<1><<<(NROWS + 63) / 64, 256, 0, stream>>>(curOb, NROWS, Uib, lbl, rlb, icol, h1b);
    hgemm<0><<<(NROWS + 63) / 64, 256, 0, stream>>>(h1b, NROWS, Uwb, nullptr, nullptr, nullptr, pre2b);
    stop_head<<<(NROWS + 63) / 64, 64, 0, stream>>>(pre2b, latW2, U_b, Uo_w, Uo_b, ctx, dir, part2);

    // ---- pred head (h1b reused as pre buffer) ----
    hgemm<0><<<TE / 64, 256, 0, stream>>>(Hb + 256, TE, Wwb, nullptr, nullptr, nullptr, h1b);
    pred_head<<<(NROWS + 63) / 64, 64, 0, stream>>>(h1b, latW, W_b, Wo_w, Wo_b,
                                                    ctx, dir, ptg, rlb, part1);

    reduce_parts<<<256, 256, 0, stream>>>(part1, part2, accum);
    finalize<<<1, 64, 0, stream>>>(accum, (float*)d_out);
}